// Round 21
// baseline (81.335 us; speedup 1.0000x reference)
//
#include <hip/hip_runtime.h>
#include <hip/hip_bf16.h>
#include <hip/hip_fp16.h>
#include <math.h>

#define NB 4
#define NP 2048
#define NC 192
#define KNN 12
#define KSEL 16
#define NEG_SLOPE 0.2f

typedef __attribute__((ext_vector_type(8))) short bf16x8;
typedef __attribute__((ext_vector_type(8))) ushort u16x8;
typedef __attribute__((ext_vector_type(4))) float f32x4;

__device__ __forceinline__ float lrelu(float x) { return x >= 0.0f ? x : NEG_SLOPE * x; }

__device__ __forceinline__ ushort f2bf(float x) {
    unsigned u = __float_as_uint(x);
    unsigned r = (u + 0x7FFFu + ((u >> 16) & 1u)) >> 16;   // RNE
    return (ushort)r;
}

// monotone f16->u16 key, packed with complemented index; self -> 0 sentinel
__device__ __forceinline__ unsigned pkkey(unsigned b, int idx, int p) {
    unsigned key = (b & 0x8000u) ? (0xFFFFu & ~b) : (b | 0x8000u);
    unsigned v = (key << 11) | (unsigned)(2047 - idx);
    return (idx == p) ? 0u : v;
}

// ---------------- device bodies ----------------------------------------------

__device__ __forceinline__ void dev_normalize(const float* __restrict__ nodes,
                                              float* __restrict__ xn,
                                              ushort* __restrict__ xh,
                                              ushort* __restrict__ xb, int blk) {
    int wave = threadIdx.x >> 6;
    int lane = threadIdx.x & 63;
    size_t pt = (size_t)blk * 4 + wave;
    const float* x = nodes + pt * NC;
    float v0 = x[lane], v1 = x[lane + 64], v2 = x[lane + 128];
    float s = v0 * v0 + v1 * v1 + v2 * v2;
    #pragma unroll
    for (int off = 32; off; off >>= 1) s += __shfl_xor(s, off, 64);
    float inv = 1.0f / fmaxf(sqrtf(s), 1e-12f);
    float f0 = v0 * inv, f1 = v1 * inv, f2 = v2 * inv;
    float* o = xn + pt * NC;
    o[lane] = f0; o[lane + 64] = f1; o[lane + 128] = f2;
    ushort* oh = xh + pt * NC;
    oh[lane] = f2bf(f0); oh[lane + 64] = f2bf(f1); oh[lane + 128] = f2bf(f2);
    ushort* ob = xb + pt * NC;
    ob[lane] = f2bf(v0); ob[lane + 64] = f2bf(v1); ob[lane + 128] = f2bf(v2);
}

// ---- kernel 1 (fused prep): normalize | w1t | w2t, branch on blockIdx -------
__global__ void __launch_bounds__(256) k_prep(const float* __restrict__ nodes,
                                              const float* __restrict__ W1,
                                              const float* __restrict__ W2,
                                              float* __restrict__ xn,
                                              ushort* __restrict__ xh,
                                              ushort* __restrict__ xb,
                                              ushort* __restrict__ w1t,
                                              ushort* __restrict__ w2t) {
    int bid = blockIdx.x;
    if (bid < NB * NP / 4) {
        dev_normalize(nodes, xn, xh, xb, bid);
    } else if (bid < NB * NP / 4 + 2 * NC * NC / 256) {
        int idx = (bid - NB * NP / 4) * 256 + threadIdx.x;
        int n = idx / NC, k = idx % NC;
        float v;
        if (n < NC) v = W1[(size_t)k * NC + n] - W1[(size_t)(k + NC) * NC + n];
        else        v = W1[(size_t)(k + NC) * NC + (n - NC)];
        w1t[idx] = f2bf(v);
    } else {
        int idx = (bid - NB * NP / 4 - 2 * NC * NC / 256) * 256 + threadIdx.x;
        int n = idx / NC, k = idx % NC;
        w2t[(size_t)n * NC + k] = f2bf(W2[(size_t)k * NC + n]);
    }
}

// ---- sim body: 128x128 tile bf16 MFMA, f16 out -------------------------------
__device__ __forceinline__ void dev_sim4(ushort (*Ah)[72], ushort (*Bh)[72],
                                         const ushort* __restrict__ xh,
                                         ushort* __restrict__ simh,
                                         int bx, int by, int bz,
                                         size_t xstride, size_t simstride) {
    const ushort* XbH = xh + (size_t)bz * xstride;
    ushort* sb = simh + (size_t)bz * simstride;
    int t = threadIdx.x;
    int w = t >> 6, l = t & 63;
    int wm = w >> 1, wn = w & 1;
    int lg = l >> 4, lr = l & 15;
    int m0 = by * 128, n0 = bx * 128;

    f32x4 acc[4][4];
    #pragma unroll
    for (int mi = 0; mi < 4; ++mi)
        #pragma unroll
        for (int ni = 0; ni < 4; ++ni)
            acc[mi][ni] = (f32x4){0.f, 0.f, 0.f, 0.f};

    int r = t >> 3, c = (t & 7) * 8;
    for (int ks = 0; ks < 3; ++ks) {
        int kb = ks * 64;
        #pragma unroll
        for (int i = 0; i < 4; ++i) {
            int row = r + 32 * i;
            *reinterpret_cast<bf16x8*>(&Ah[row][c]) =
                *reinterpret_cast<const bf16x8*>(&XbH[(size_t)(m0 + row) * NC + kb + c]);
            *reinterpret_cast<bf16x8*>(&Bh[row][c]) =
                *reinterpret_cast<const bf16x8*>(&XbH[(size_t)(n0 + row) * NC + kb + c]);
        }
        __syncthreads();
        #pragma unroll
        for (int ksub = 0; ksub < 2; ++ksub) {
            int ko = ksub * 32 + 8 * lg;
            bf16x8 af[4], bf[4];
            #pragma unroll
            for (int f = 0; f < 4; ++f) {
                af[f] = *reinterpret_cast<const bf16x8*>(&Ah[wm * 64 + f * 16 + lr][ko]);
                bf[f] = *reinterpret_cast<const bf16x8*>(&Bh[wn * 64 + f * 16 + lr][ko]);
            }
            #pragma unroll
            for (int mi = 0; mi < 4; ++mi)
                #pragma unroll
                for (int ni = 0; ni < 4; ++ni)
                    acc[mi][ni] = __builtin_amdgcn_mfma_f32_16x16x32_bf16(af[mi], bf[ni], acc[mi][ni], 0, 0, 0);
        }
        __syncthreads();
    }
    #pragma unroll
    for (int mi = 0; mi < 4; ++mi)
        #pragma unroll
        for (int j = 0; j < 4; ++j) {
            int row = m0 + wm * 64 + mi * 16 + lg * 4 + j;
            ushort* hrow = sb + (size_t)row * NP;
            #pragma unroll
            for (int ni = 0; ni < 4; ++ni) {
                __half h = __float2half(acc[mi][ni][j]);
                hrow[n0 + wn * 64 + ni * 16 + lr] = *reinterpret_cast<const ushort*>(&h);
            }
        }
}

// ---- uv body: [U'|V] = Xb @ w1t^T via MFMA; bias fused; bf16 out -------------
#define UVM 32
__device__ __forceinline__ void dev_uv2(ushort (*xs)[200],
                                        const ushort* __restrict__ xb,
                                        const ushort* __restrict__ w1t,
                                        const float* __restrict__ b1,
                                        ushort* __restrict__ up,
                                        ushort* __restrict__ vv, int blk) {
    int t = threadIdx.x;
    int w = t >> 6, l = t & 63;
    int lg = l >> 4, lr = l & 15;
    int p0 = blk * UVM;
    for (int i = t; i < UVM * 24; i += 256) {
        int row = i / 24, c = (i % 24) * 8;
        *reinterpret_cast<bf16x8*>(&xs[row][c]) =
            *reinterpret_cast<const bf16x8*>(&xb[(size_t)(p0 + row) * NC + c]);
    }
    __syncthreads();
    int n0 = w * 96;
    f32x4 acc[2][6];
    #pragma unroll
    for (int mt = 0; mt < 2; ++mt)
        #pragma unroll
        for (int nt = 0; nt < 6; ++nt)
            acc[mt][nt] = (f32x4){0.f, 0.f, 0.f, 0.f};
    #pragma unroll
    for (int ks = 0; ks < 6; ++ks) {
        bf16x8 bfr[6];
        #pragma unroll
        for (int nt = 0; nt < 6; ++nt)
            bfr[nt] = *reinterpret_cast<const bf16x8*>(
                &w1t[(size_t)(n0 + nt * 16 + lr) * NC + ks * 32 + lg * 8]);
        bf16x8 a0 = *reinterpret_cast<const bf16x8*>(&xs[lr][ks * 32 + lg * 8]);
        bf16x8 a1 = *reinterpret_cast<const bf16x8*>(&xs[16 + lr][ks * 32 + lg * 8]);
        #pragma unroll
        for (int nt = 0; nt < 6; ++nt) {
            acc[0][nt] = __builtin_amdgcn_mfma_f32_16x16x32_bf16(a0, bfr[nt], acc[0][nt], 0, 0, 0);
            acc[1][nt] = __builtin_amdgcn_mfma_f32_16x16x32_bf16(a1, bfr[nt], acc[1][nt], 0, 0, 0);
        }
    }
    bool isU = (n0 < NC);
    #pragma unroll
    for (int nt = 0; nt < 6; ++nt) {
        int col = n0 + nt * 16 + lr;
        float bb = isU ? b1[col] : 0.f;
        int ocol = isU ? col : col - NC;
        ushort* dst = isU ? up : vv;
        #pragma unroll
        for (int mt = 0; mt < 2; ++mt)
            #pragma unroll
            for (int j = 0; j < 4; ++j) {
                int pt = p0 + mt * 16 + lg * 4 + j;
                dst[(size_t)pt * NC + ocol] = f2bf(acc[mt][nt][j] + bb);
            }
    }
}

// ---- kernel 2 (fused): uv2 (blocks 0..255) | sim4 (blocks 256..1279) ---------
__global__ void __launch_bounds__(256) k_uvsim(const ushort* __restrict__ xb,
                                               const ushort* __restrict__ w1t,
                                               const float* __restrict__ b1,
                                               ushort* __restrict__ up,
                                               ushort* __restrict__ vv,
                                               const ushort* __restrict__ xh,
                                               ushort* __restrict__ simh) {
    extern __shared__ char smem[];
    if (blockIdx.x < NB * NP / UVM) {
        dev_uv2((ushort(*)[200])smem, xb, w1t, b1, up, vv, blockIdx.x);
    } else {
        int sb_ = blockIdx.x - NB * NP / UVM;
        int bz = sb_ >> 8, rem = sb_ & 255, by = rem >> 4, bx = rem & 15;
        ushort (*Ah)[72] = (ushort(*)[72])smem;
        ushort (*Bh)[72] = Ah + 128;
        dev_sim4(Ah, Bh, xh, simh, bx, by, bz, (size_t)NP * NC, (size_t)NP * NP);
    }
}

// ---- standalone wrappers (ws-frugal fallback path) ---------------------------
__global__ void __launch_bounds__(256) k_uv2(const ushort* __restrict__ xb,
                                             const ushort* __restrict__ w1t,
                                             const float* __restrict__ b1,
                                             ushort* __restrict__ up,
                                             ushort* __restrict__ vv) {
    __shared__ ushort xs[UVM][200];
    dev_uv2(xs, xb, w1t, b1, up, vv, blockIdx.x);
}

__global__ void __launch_bounds__(256) k_sim4(const ushort* __restrict__ xh,
                                              ushort* __restrict__ simh,
                                              size_t xstride, size_t simstride) {
    __shared__ ushort Ah[128][72];
    __shared__ ushort Bh[128][72];
    dev_sim4(Ah, Bh, xh, simh, blockIdx.x, blockIdx.y, blockIdx.z, xstride, simstride);
}

// rare fallback: u32 insert list depth 16 + 16 extraction rounds (forceinline:
// pointer-escape would spill h8 to scratch — R12 lesson, 33 MB WRITE_SIZE).
__device__ __forceinline__ int topk_fb(const u16x8 h8[4], int p, int lane) {
    unsigned tv[16];
    #pragma unroll
    for (int q = 0; q < 16; ++q) tv[q] = 0u;
    #pragma unroll
    for (int i = 0; i < 4; ++i)
        #pragma unroll
        for (int j = 0; j < 8; ++j) {
            unsigned v = pkkey((unsigned)(ushort)h8[i][j], lane * 8 + i * 512 + j, p);
            if (v > tv[0]) {
                bool cg[16];
                #pragma unroll
                for (int q = 0; q < 16; ++q) cg[q] = v > tv[q];
                #pragma unroll
                for (int q = 0; q < 15; ++q)
                    tv[q] = cg[q + 1] ? tv[q + 1] : (cg[q] ? v : tv[q]);
                tv[15] = cg[15] ? v : tv[15];
            }
        }
    unsigned mp = 0u;
    #pragma unroll
    for (int rr = 0; rr < 16; ++rr) {
        unsigned bv = tv[15];
        #pragma unroll
        for (int off = 1; off < 64; off <<= 1) {
            unsigned ov = __shfl_xor(bv, off, 64);
            bv = ov > bv ? ov : bv;
        }
        if ((lane >> 2) == rr) mp = bv;
        if (bv == tv[15]) {
            #pragma unroll
            for (int s = 15; s > 0; --s) tv[s] = tv[s - 1];
            tv[0] = 0u;
        }
    }
    return (mp == 0u) ? -1 : (int)(2047u - (mp & 0x7FFu));
}

// ---- selection body: one row per wave; atomic-compact (no count/scan pass) ---
__device__ __forceinline__ void dev_topk_row(const ushort* __restrict__ sr,
                                             const float* __restrict__ xb,
                                             int p, unsigned* candw, int* cntw,
                                             int lane, int* out12) {
    u16x8 h8[4];
    #pragma unroll
    for (int i = 0; i < 4; ++i)
        h8[i] = *reinterpret_cast<const u16x8*>(sr + lane * 8 + i * 512);

    unsigned lmax = 0;
    #pragma unroll
    for (int i = 0; i < 4; ++i)
        #pragma unroll
        for (int j = 0; j < 8; ++j) {
            unsigned v = pkkey((unsigned)(ushort)h8[i][j], lane * 8 + i * 512 + j, p);
            lmax = v > lmax ? v : lmax;
        }

    unsigned sm = lmax;
    #pragma unroll
    for (int k = 2; k <= 64; k <<= 1) {
        #pragma unroll
        for (int j = k >> 1; j >= 1; j >>= 1) {
            unsigned ov = __shfl_xor(sm, j, 64);
            bool keep_lo = (((lane & k) != 0) == ((lane & j) == 0));
            unsigned lo = sm < ov ? sm : ov, hi = sm < ov ? ov : sm;
            sm = keep_lo ? lo : hi;
        }
    }
    unsigned theta = __shfl(sm, KSEL, 64);   // 17th-largest lane-max

    candw[lane] = 0u;
    if (lane == 0) *cntw = 0;
    asm volatile("s_waitcnt lgkmcnt(0)" ::: "memory");
    #pragma unroll
    for (int i = 0; i < 4; ++i)
        #pragma unroll
        for (int j = 0; j < 8; ++j) {
            unsigned v = pkkey((unsigned)(ushort)h8[i][j], lane * 8 + i * 512 + j, p);
            if (v > theta) {
                int pos = atomicAdd(cntw, 1);
                if (pos < 64) candw[pos] = v;
            }
        }
    asm volatile("s_waitcnt lgkmcnt(0)" ::: "memory");
    int total = *cntw;
    asm volatile("s_waitcnt lgkmcnt(0)" ::: "memory");

    int my_q;
    if (total <= 64) {
        unsigned v = candw[lane];
        #pragma unroll
        for (int k = 2; k <= 64; k <<= 1) {
            #pragma unroll
            for (int j = k >> 1; j >= 1; j >>= 1) {
                unsigned ov = __shfl_xor(v, j, 64);
                bool keep_lo = (((lane & k) != 0) == ((lane & j) == 0));
                unsigned lo = v < ov ? v : ov, hi = v < ov ? ov : v;
                v = keep_lo ? lo : hi;
            }
        }
        unsigned mp = __shfl(v, lane >> 2, 64);
        my_q = (mp == 0u) ? -1 : (int)(2047u - (mp & 0x7FFu));
    } else {
        my_q = topk_fb(h8, p, lane);   // rare overflow path
    }

    int qa = my_q < 0 ? 0 : my_q;
    const float* cp = xb + (size_t)p * NC + (lane & 3) * 48;
    const float* cq = xb + (size_t)qa * NC + (lane & 3) * 48;
    float dot = 0.f;
    #pragma unroll
    for (int i = 0; i < 12; ++i) {
        float4 a = *reinterpret_cast<const float4*>(cp + i * 4);
        float4 bq = *reinterpret_cast<const float4*>(cq + i * 4);
        dot += a.x * bq.x + a.y * bq.y + a.z * bq.z + a.w * bq.w;
    }
    dot += __shfl_xor(dot, 1, 64);
    dot += __shfl_xor(dot, 2, 64);
    int g = lane >> 2;
    int rank = 0;
    #pragma unroll
    for (int j = 0; j < KSEL; ++j) {
        float vj = __shfl(dot, j * 4, 64);
        int   qj = __shfl(my_q, j * 4, 64);
        if (j != g && qj >= 0 && (vj > dot || (vj == dot && qj < my_q))) ++rank;
    }
    bool keep = ((lane & 3) == 0) && (my_q >= 0) && (rank < KNN);
    unsigned long long mask = __ballot(keep);
    int pos = __popcll(mask & ((1ull << lane) - 1));
    if (keep) out12[pos] = my_q;
}

// -- kernel 3: standalone top-k (256 thr -> 8 waves/SIMD residency) ------------
__global__ void __launch_bounds__(256) k_topk7(const ushort* __restrict__ simh,
                                               const float* __restrict__ xn,
                                               int* __restrict__ knn,
                                               size_t simstride, size_t xstride) {
    __shared__ unsigned cand[4][64];
    __shared__ int ccnt[4];
    int wv = threadIdx.x >> 6, lane = threadIdx.x & 63;
    int row = blockIdx.x * 4 + wv;
    int b = row / NP, p = row % NP;
    dev_topk_row(simh + (size_t)b * simstride + (size_t)p * NP,
                 xn + (size_t)b * xstride, p, cand[wv], &ccnt[wv], lane,
                 knn + (size_t)row * KNN);
}

// ---- edge body: one point per wave; 3-deep gather ring + setprio MFMA --------
__device__ __forceinline__ bf16x8 packh2(bf16x8 u, bf16x8 v) {
    union { bf16x8 v8; ushort us[8]; } U, V, R;
    U.v8 = u; V.v8 = v;
    #pragma unroll
    for (int i = 0; i < 8; i += 2) {
        float a0 = __uint_as_float((unsigned)U.us[i] << 16)
                 + __uint_as_float((unsigned)V.us[i] << 16);
        float a1 = __uint_as_float((unsigned)U.us[i + 1] << 16)
                 + __uint_as_float((unsigned)V.us[i + 1] << 16);
        __hip_bfloat162 h2 = __float22bfloat162_rn(make_float2(lrelu(a0), lrelu(a1)));
        R.us[i]     = *reinterpret_cast<const ushort*>(&h2.x);
        R.us[i + 1] = *reinterpret_cast<const ushort*>(&h2.y);
    }
    return R.v8;
}

__device__ __forceinline__ void dev_edge_point(const ushort* __restrict__ up,
                                               const ushort* __restrict__ vv,
                                               int q0, int pt0,
                                               ushort (*w2s)[200], float* aggsw,
                                               const float* __restrict__ b2,
                                               const float* __restrict__ gamma,
                                               const float* __restrict__ beta,
                                               float* __restrict__ out,
                                               int l, int lg, int lr) {
    int b = pt0 / NP;
    const ushort* u0p = up + (size_t)pt0 * NC + 8 * lg;
    const ushort* v0p = vv + ((size_t)b * NP + q0) * NC + 8 * lg;

    f32x4 acc[12];
    #pragma unroll
    for (int nt = 0; nt < 12; ++nt) acc[nt] = (f32x4){0.f, 0.f, 0.f, 0.f};

    bf16x8 sU[3], sV[3];
#define LDST(ph, ks) do { \
        sU[ph] = *reinterpret_cast<const bf16x8*>(u0p + (ks) * 32); \
        sV[ph] = *reinterpret_cast<const bf16x8*>(v0p + (ks) * 32); \
    } while (0)

    LDST(0, 0); LDST(1, 1); LDST(2, 2);
    #pragma unroll
    for (int ks = 0; ks < 6; ++ks) {
        int ph = ks % 3;
        bf16x8 a0 = packh2(sU[ph], sV[ph]);
        if (ks < 3) LDST(ph, ks + 3);
        __builtin_amdgcn_s_setprio(1);
        #pragma unroll
        for (int nt = 0; nt < 12; ++nt) {
            bf16x8 bfr = *reinterpret_cast<const bf16x8*>(&w2s[nt * 16 + lr][ks * 32 + lg * 8]);
            acc[nt] = __builtin_amdgcn_mfma_f32_16x16x32_bf16(a0, bfr, acc[nt], 0, 0, 0);
        }
        __builtin_amdgcn_s_setprio(0);
    }
#undef LDST

    #pragma unroll
    for (int nt = 0; nt < 12; ++nt) {
        float bb = b2[nt * 16 + lr];
        float s = 0.f;
        if (lg < 3) {
            #pragma unroll
            for (int j = 0; j < 4; ++j) s += lrelu(acc[nt][j] + bb);
        }
        s += __shfl_xor(s, 16, 64);
        s += __shfl_xor(s, 32, 64);
        if (lg == 0) aggsw[nt * 16 + lr] = s * (1.0f / KNN);
    }
    asm volatile("s_waitcnt lgkmcnt(0)" ::: "memory");

    float a0 = aggsw[l], a1 = aggsw[l + 64], a2 = aggsw[l + 128];
    float s = a0 + a1 + a2;
    #pragma unroll
    for (int off = 32; off; off >>= 1) s += __shfl_xor(s, off, 64);
    float mu = s / (float)NC;
    float d0 = a0 - mu, d1 = a1 - mu, d2 = a2 - mu;
    float vs = d0 * d0 + d1 * d1 + d2 * d2;
    #pragma unroll
    for (int off = 32; off; off >>= 1) vs += __shfl_xor(vs, off, 64);
    float rstd = 1.0f / sqrtf(vs / (float)NC + 1e-5f);
    float* o = out + (size_t)pt0 * NC;
    o[l]       = d0 * rstd * gamma[l]       + beta[l];
    o[l + 64]  = d1 * rstd * gamma[l + 64]  + beta[l + 64];
    o[l + 128] = d2 * rstd * gamma[l + 128] + beta[l + 128];
}

#define EW 16   // waves/block, 1 point each

// ---- kernel 5: standalone edge MLP -------------------------------------------
__global__ void __launch_bounds__(1024, 4) k_edge7(const ushort* __restrict__ up,
                                                   const ushort* __restrict__ vv,
                                                   const int* __restrict__ knn,
                                                   const ushort* __restrict__ w2t,
                                                   const float* __restrict__ b2,
                                                   const float* __restrict__ gamma,
                                                   const float* __restrict__ beta,
                                                   float* __restrict__ out) {
    __shared__ ushort w2s[NC][200];
    __shared__ float aggs[EW][NC];
    int t = threadIdx.x;
    int wv = t >> 6, l = t & 63;
    int lg = l >> 4, lr = l & 15;

    int pt0 = blockIdx.x * EW + wv;
    int lre = lr < KNN ? lr : KNN - 1;
    int q0 = knn[(size_t)pt0 * KNN + lre];

    for (int i = t; i < NC * 24; i += 1024) {
        int r_ = i / 24, c_ = i % 24;
        *reinterpret_cast<bf16x8*>(&w2s[r_][c_ * 8]) =
            *reinterpret_cast<const bf16x8*>(&w2t[(size_t)r_ * NC + c_ * 8]);
    }
    __syncthreads();

    dev_edge_point(up, vv, q0, pt0, w2s, aggs[wv], b2, gamma, beta, out, l, lg, lr);
}

extern "C" void kernel_launch(void* const* d_in, const int* in_sizes, int n_in,
                              void* d_out, int out_size, void* d_ws, size_t ws_size,
                              hipStream_t stream) {
    const float* nodes = (const float*)d_in[0];
    const float* W1    = (const float*)d_in[1];
    const float* b1    = (const float*)d_in[2];
    const float* W2    = (const float*)d_in[3];
    const float* b2    = (const float*)d_in[4];
    const float* gamma = (const float*)d_in[5];
    const float* beta  = (const float*)d_in[6];
    float* out = (float*)d_out;

    const size_t BPC = (size_t)NB * NP * NC;
    float*  xn  = (float*)d_ws;                        // B*P*C f32
    ushort* up  = (ushort*)(xn + BPC);                 // B*P*C bf16
    ushort* vv  = up + BPC;                            // B*P*C bf16
    ushort* xh  = vv + BPC;                            // B*P*C bf16 (normalized)
    ushort* xb  = xh + BPC;                            // B*P*C bf16 (raw)
    int*    knn = (int*)(xb + BPC);                    // B*P*K
    ushort* w2t = (ushort*)(knn + (size_t)NB * NP * KNN); // C*C bf16
    ushort* w1t = w2t + (size_t)NC * NC;               // 2C*C bf16
    ushort* simh = (ushort*)(((uintptr_t)(w1t + (size_t)2 * NC * NC) + 15) & ~(uintptr_t)15);

    size_t fixed_bytes = (size_t)((char*)simh - (char*)d_ws);
    bool full = ws_size >= fixed_bytes + (size_t)NB * NP * NP * 2;

    int prep_grid = NB * NP / 4 + 2 * NC * NC / 256 + NC * NC / 256;   // 2048+288+144
    k_prep<<<prep_grid, 256, 0, stream>>>(nodes, W1, W2, xn, xh, xb, w1t, w2t);
    if (full) {
        k_uvsim<<<NB * NP / UVM + 16 * NB * (NP / 128), 256, 36864, stream>>>(
            xb, w1t, b1, up, vv, xh, simh);
        k_topk7<<<NB * NP / 4, 256, 0, stream>>>(simh, xn, knn,
                                                 (size_t)NP * NP, (size_t)NP * NC);
        k_edge7<<<NB * NP / EW, 1024, 0, stream>>>(up, vv, knn, w2t, b2, gamma, beta, out);
    } else {
        k_uv2<<<NB * NP / UVM, 256, 0, stream>>>(xb, w1t, b1, up, vv);
        for (int b = 0; b < NB; ++b) {
            k_sim4<<<dim3(NP / 128, NP / 128, 1), 256, 0, stream>>>(xh + (size_t)b * NP * NC, simh, 0, 0);
            k_topk7<<<NP / 4, 256, 0, stream>>>(simh, xn + (size_t)b * NP * NC,
                                                knn + (size_t)b * NP * KNN, 0, 0);
        }
        k_edge7<<<NB * NP / EW, 1024, 0, stream>>>(up, vv, knn, w2t, b2, gamma, beta, out);
    }
}

// Round 22
// 76.660 us; speedup vs baseline: 1.0610x; 1.0610x over previous
//
#include <hip/hip_runtime.h>
#include <hip/hip_bf16.h>
#include <hip/hip_fp16.h>
#include <math.h>

#define NB 4
#define NP 2048
#define NC 192
#define KNN 12
#define KSEL 16
#define NEG_SLOPE 0.2f

typedef __attribute__((ext_vector_type(8))) short bf16x8;
typedef __attribute__((ext_vector_type(8))) ushort u16x8;
typedef __attribute__((ext_vector_type(4))) float f32x4;

__device__ __forceinline__ float lrelu(float x) { return x >= 0.0f ? x : NEG_SLOPE * x; }

__device__ __forceinline__ ushort f2bf(float x) {
    unsigned u = __float_as_uint(x);
    unsigned r = (u + 0x7FFFu + ((u >> 16) & 1u)) >> 16;   // RNE
    return (ushort)r;
}

// monotone f16->u16 key, packed with complemented index; self -> 0 sentinel
__device__ __forceinline__ unsigned pkkey(unsigned b, int idx, int p) {
    unsigned key = (b & 0x8000u) ? (0xFFFFu & ~b) : (b | 0x8000u);
    unsigned v = (key << 11) | (unsigned)(2047 - idx);
    return (idx == p) ? 0u : v;
}

// ---------------- device bodies ----------------------------------------------

__device__ __forceinline__ void dev_normalize(const float* __restrict__ nodes,
                                              float* __restrict__ xn,
                                              ushort* __restrict__ xh,
                                              ushort* __restrict__ xb, int blk) {
    int wave = threadIdx.x >> 6;
    int lane = threadIdx.x & 63;
    size_t pt = (size_t)blk * 4 + wave;
    const float* x = nodes + pt * NC;
    float v0 = x[lane], v1 = x[lane + 64], v2 = x[lane + 128];
    float s = v0 * v0 + v1 * v1 + v2 * v2;
    #pragma unroll
    for (int off = 32; off; off >>= 1) s += __shfl_xor(s, off, 64);
    float inv = 1.0f / fmaxf(sqrtf(s), 1e-12f);
    float f0 = v0 * inv, f1 = v1 * inv, f2 = v2 * inv;
    float* o = xn + pt * NC;
    o[lane] = f0; o[lane + 64] = f1; o[lane + 128] = f2;
    ushort* oh = xh + pt * NC;
    oh[lane] = f2bf(f0); oh[lane + 64] = f2bf(f1); oh[lane + 128] = f2bf(f2);
    ushort* ob = xb + pt * NC;
    ob[lane] = f2bf(v0); ob[lane + 64] = f2bf(v1); ob[lane + 128] = f2bf(v2);
}

// ---- kernel 1 (fused prep): normalize | w1t | w2t, branch on blockIdx -------
__global__ void __launch_bounds__(256) k_prep(const float* __restrict__ nodes,
                                              const float* __restrict__ W1,
                                              const float* __restrict__ W2,
                                              float* __restrict__ xn,
                                              ushort* __restrict__ xh,
                                              ushort* __restrict__ xb,
                                              ushort* __restrict__ w1t,
                                              ushort* __restrict__ w2t) {
    int bid = blockIdx.x;
    if (bid < NB * NP / 4) {
        dev_normalize(nodes, xn, xh, xb, bid);
    } else if (bid < NB * NP / 4 + 2 * NC * NC / 256) {
        int idx = (bid - NB * NP / 4) * 256 + threadIdx.x;
        int n = idx / NC, k = idx % NC;
        float v;
        if (n < NC) v = W1[(size_t)k * NC + n] - W1[(size_t)(k + NC) * NC + n];
        else        v = W1[(size_t)(k + NC) * NC + (n - NC)];
        w1t[idx] = f2bf(v);
    } else {
        int idx = (bid - NB * NP / 4 - 2 * NC * NC / 256) * 256 + threadIdx.x;
        int n = idx / NC, k = idx % NC;
        w2t[(size_t)n * NC + k] = f2bf(W2[(size_t)k * NC + n]);
    }
}

// ---- sim body: 128x128 tile bf16 MFMA, f16 out -------------------------------
__device__ __forceinline__ void dev_sim4(ushort (*Ah)[72], ushort (*Bh)[72],
                                         const ushort* __restrict__ xh,
                                         ushort* __restrict__ simh,
                                         int bx, int by, int bz,
                                         size_t xstride, size_t simstride) {
    const ushort* XbH = xh + (size_t)bz * xstride;
    ushort* sb = simh + (size_t)bz * simstride;
    int t = threadIdx.x;
    int w = t >> 6, l = t & 63;
    int wm = w >> 1, wn = w & 1;
    int lg = l >> 4, lr = l & 15;
    int m0 = by * 128, n0 = bx * 128;

    f32x4 acc[4][4];
    #pragma unroll
    for (int mi = 0; mi < 4; ++mi)
        #pragma unroll
        for (int ni = 0; ni < 4; ++ni)
            acc[mi][ni] = (f32x4){0.f, 0.f, 0.f, 0.f};

    int r = t >> 3, c = (t & 7) * 8;
    for (int ks = 0; ks < 3; ++ks) {
        int kb = ks * 64;
        #pragma unroll
        for (int i = 0; i < 4; ++i) {
            int row = r + 32 * i;
            *reinterpret_cast<bf16x8*>(&Ah[row][c]) =
                *reinterpret_cast<const bf16x8*>(&XbH[(size_t)(m0 + row) * NC + kb + c]);
            *reinterpret_cast<bf16x8*>(&Bh[row][c]) =
                *reinterpret_cast<const bf16x8*>(&XbH[(size_t)(n0 + row) * NC + kb + c]);
        }
        __syncthreads();
        #pragma unroll
        for (int ksub = 0; ksub < 2; ++ksub) {
            int ko = ksub * 32 + 8 * lg;
            bf16x8 af[4], bf[4];
            #pragma unroll
            for (int f = 0; f < 4; ++f) {
                af[f] = *reinterpret_cast<const bf16x8*>(&Ah[wm * 64 + f * 16 + lr][ko]);
                bf[f] = *reinterpret_cast<const bf16x8*>(&Bh[wn * 64 + f * 16 + lr][ko]);
            }
            #pragma unroll
            for (int mi = 0; mi < 4; ++mi)
                #pragma unroll
                for (int ni = 0; ni < 4; ++ni)
                    acc[mi][ni] = __builtin_amdgcn_mfma_f32_16x16x32_bf16(af[mi], bf[ni], acc[mi][ni], 0, 0, 0);
        }
        __syncthreads();
    }
    #pragma unroll
    for (int mi = 0; mi < 4; ++mi)
        #pragma unroll
        for (int j = 0; j < 4; ++j) {
            int row = m0 + wm * 64 + mi * 16 + lg * 4 + j;
            ushort* hrow = sb + (size_t)row * NP;
            #pragma unroll
            for (int ni = 0; ni < 4; ++ni) {
                __half h = __float2half(acc[mi][ni][j]);
                hrow[n0 + wn * 64 + ni * 16 + lr] = *reinterpret_cast<const ushort*>(&h);
            }
        }
}

// ---- uv body: [U'|V] = Xb @ w1t^T via MFMA; bias fused; bf16 out -------------
#define UVM 32
__device__ __forceinline__ void dev_uv2(ushort (*xs)[200],
                                        const ushort* __restrict__ xb,
                                        const ushort* __restrict__ w1t,
                                        const float* __restrict__ b1,
                                        ushort* __restrict__ up,
                                        ushort* __restrict__ vv, int blk) {
    int t = threadIdx.x;
    int w = t >> 6, l = t & 63;
    int lg = l >> 4, lr = l & 15;
    int p0 = blk * UVM;
    for (int i = t; i < UVM * 24; i += 256) {
        int row = i / 24, c = (i % 24) * 8;
        *reinterpret_cast<bf16x8*>(&xs[row][c]) =
            *reinterpret_cast<const bf16x8*>(&xb[(size_t)(p0 + row) * NC + c]);
    }
    __syncthreads();
    int n0 = w * 96;
    f32x4 acc[2][6];
    #pragma unroll
    for (int mt = 0; mt < 2; ++mt)
        #pragma unroll
        for (int nt = 0; nt < 6; ++nt)
            acc[mt][nt] = (f32x4){0.f, 0.f, 0.f, 0.f};
    #pragma unroll
    for (int ks = 0; ks < 6; ++ks) {
        bf16x8 bfr[6];
        #pragma unroll
        for (int nt = 0; nt < 6; ++nt)
            bfr[nt] = *reinterpret_cast<const bf16x8*>(
                &w1t[(size_t)(n0 + nt * 16 + lr) * NC + ks * 32 + lg * 8]);
        bf16x8 a0 = *reinterpret_cast<const bf16x8*>(&xs[lr][ks * 32 + lg * 8]);
        bf16x8 a1 = *reinterpret_cast<const bf16x8*>(&xs[16 + lr][ks * 32 + lg * 8]);
        #pragma unroll
        for (int nt = 0; nt < 6; ++nt) {
            acc[0][nt] = __builtin_amdgcn_mfma_f32_16x16x32_bf16(a0, bfr[nt], acc[0][nt], 0, 0, 0);
            acc[1][nt] = __builtin_amdgcn_mfma_f32_16x16x32_bf16(a1, bfr[nt], acc[1][nt], 0, 0, 0);
        }
    }
    bool isU = (n0 < NC);
    #pragma unroll
    for (int nt = 0; nt < 6; ++nt) {
        int col = n0 + nt * 16 + lr;
        float bb = isU ? b1[col] : 0.f;
        int ocol = isU ? col : col - NC;
        ushort* dst = isU ? up : vv;
        #pragma unroll
        for (int mt = 0; mt < 2; ++mt)
            #pragma unroll
            for (int j = 0; j < 4; ++j) {
                int pt = p0 + mt * 16 + lg * 4 + j;
                dst[(size_t)pt * NC + ocol] = f2bf(acc[mt][nt][j] + bb);
            }
    }
}

// ---- kernel 2 (fused): uv2 (blocks 0..255) | sim4 (blocks 256..1279) ---------
__global__ void __launch_bounds__(256) k_uvsim(const ushort* __restrict__ xb,
                                               const ushort* __restrict__ w1t,
                                               const float* __restrict__ b1,
                                               ushort* __restrict__ up,
                                               ushort* __restrict__ vv,
                                               const ushort* __restrict__ xh,
                                               ushort* __restrict__ simh) {
    extern __shared__ char smem[];
    if (blockIdx.x < NB * NP / UVM) {
        dev_uv2((ushort(*)[200])smem, xb, w1t, b1, up, vv, blockIdx.x);
    } else {
        int sb_ = blockIdx.x - NB * NP / UVM;
        int bz = sb_ >> 8, rem = sb_ & 255, by = rem >> 4, bx = rem & 15;
        ushort (*Ah)[72] = (ushort(*)[72])smem;
        ushort (*Bh)[72] = Ah + 128;
        dev_sim4(Ah, Bh, xh, simh, bx, by, bz, (size_t)NP * NC, (size_t)NP * NP);
    }
}

// ---- standalone wrappers (ws-frugal fallback path) ---------------------------
__global__ void __launch_bounds__(256) k_uv2(const ushort* __restrict__ xb,
                                             const ushort* __restrict__ w1t,
                                             const float* __restrict__ b1,
                                             ushort* __restrict__ up,
                                             ushort* __restrict__ vv) {
    __shared__ ushort xs[UVM][200];
    dev_uv2(xs, xb, w1t, b1, up, vv, blockIdx.x);
}

__global__ void __launch_bounds__(256) k_sim4(const ushort* __restrict__ xh,
                                              ushort* __restrict__ simh,
                                              size_t xstride, size_t simstride) {
    __shared__ ushort Ah[128][72];
    __shared__ ushort Bh[128][72];
    dev_sim4(Ah, Bh, xh, simh, blockIdx.x, blockIdx.y, blockIdx.z, xstride, simstride);
}

// rare fallback: u32 insert list depth 16 + 16 extraction rounds (forceinline:
// pointer-escape would spill h8 to scratch — R12 lesson, 33 MB WRITE_SIZE).
__device__ __forceinline__ int topk_fb(const u16x8 h8[4], int p, int lane) {
    unsigned tv[16];
    #pragma unroll
    for (int q = 0; q < 16; ++q) tv[q] = 0u;
    #pragma unroll
    for (int i = 0; i < 4; ++i)
        #pragma unroll
        for (int j = 0; j < 8; ++j) {
            unsigned v = pkkey((unsigned)(ushort)h8[i][j], lane * 8 + i * 512 + j, p);
            if (v > tv[0]) {
                bool cg[16];
                #pragma unroll
                for (int q = 0; q < 16; ++q) cg[q] = v > tv[q];
                #pragma unroll
                for (int q = 0; q < 15; ++q)
                    tv[q] = cg[q + 1] ? tv[q + 1] : (cg[q] ? v : tv[q]);
                tv[15] = cg[15] ? v : tv[15];
            }
        }
    unsigned mp = 0u;
    #pragma unroll
    for (int rr = 0; rr < 16; ++rr) {
        unsigned bv = tv[15];
        #pragma unroll
        for (int off = 1; off < 64; off <<= 1) {
            unsigned ov = __shfl_xor(bv, off, 64);
            bv = ov > bv ? ov : bv;
        }
        if ((lane >> 2) == rr) mp = bv;
        if (bv == tv[15]) {
            #pragma unroll
            for (int s = 15; s > 0; --s) tv[s] = tv[s - 1];
            tv[0] = 0u;
        }
    }
    return (mp == 0u) ? -1 : (int)(2047u - (mp & 0x7FFu));
}

// ---- selection body: one row per wave; atomic-compact (no count/scan pass) ---
__device__ __forceinline__ void dev_topk_row(const ushort* __restrict__ sr,
                                             const float* __restrict__ xb,
                                             int p, unsigned* candw, int* cntw,
                                             int lane, int* out12) {
    u16x8 h8[4];
    #pragma unroll
    for (int i = 0; i < 4; ++i)
        h8[i] = *reinterpret_cast<const u16x8*>(sr + lane * 8 + i * 512);

    unsigned lmax = 0;
    #pragma unroll
    for (int i = 0; i < 4; ++i)
        #pragma unroll
        for (int j = 0; j < 8; ++j) {
            unsigned v = pkkey((unsigned)(ushort)h8[i][j], lane * 8 + i * 512 + j, p);
            lmax = v > lmax ? v : lmax;
        }

    unsigned sm = lmax;
    #pragma unroll
    for (int k = 2; k <= 64; k <<= 1) {
        #pragma unroll
        for (int j = k >> 1; j >= 1; j >>= 1) {
            unsigned ov = __shfl_xor(sm, j, 64);
            bool keep_lo = (((lane & k) != 0) == ((lane & j) == 0));
            unsigned lo = sm < ov ? sm : ov, hi = sm < ov ? ov : sm;
            sm = keep_lo ? lo : hi;
        }
    }
    unsigned theta = __shfl(sm, KSEL, 64);   // 17th-largest lane-max

    candw[lane] = 0u;
    if (lane == 0) *cntw = 0;
    asm volatile("s_waitcnt lgkmcnt(0)" ::: "memory");
    #pragma unroll
    for (int i = 0; i < 4; ++i)
        #pragma unroll
        for (int j = 0; j < 8; ++j) {
            unsigned v = pkkey((unsigned)(ushort)h8[i][j], lane * 8 + i * 512 + j, p);
            if (v > theta) {
                int pos = atomicAdd(cntw, 1);
                if (pos < 64) candw[pos] = v;
            }
        }
    asm volatile("s_waitcnt lgkmcnt(0)" ::: "memory");
    int total = *cntw;
    asm volatile("s_waitcnt lgkmcnt(0)" ::: "memory");

    int my_q;
    if (total <= 64) {
        unsigned v = candw[lane];
        #pragma unroll
        for (int k = 2; k <= 64; k <<= 1) {
            #pragma unroll
            for (int j = k >> 1; j >= 1; j >>= 1) {
                unsigned ov = __shfl_xor(v, j, 64);
                bool keep_lo = (((lane & k) != 0) == ((lane & j) == 0));
                unsigned lo = v < ov ? v : ov, hi = v < ov ? ov : v;
                v = keep_lo ? lo : hi;
            }
        }
        unsigned mp = __shfl(v, lane >> 2, 64);
        my_q = (mp == 0u) ? -1 : (int)(2047u - (mp & 0x7FFu));
    } else {
        my_q = topk_fb(h8, p, lane);   // rare overflow path
    }

    int qa = my_q < 0 ? 0 : my_q;
    const float* cp = xb + (size_t)p * NC + (lane & 3) * 48;
    const float* cq = xb + (size_t)qa * NC + (lane & 3) * 48;
    float dot = 0.f;
    #pragma unroll
    for (int i = 0; i < 12; ++i) {
        float4 a = *reinterpret_cast<const float4*>(cp + i * 4);
        float4 bq = *reinterpret_cast<const float4*>(cq + i * 4);
        dot += a.x * bq.x + a.y * bq.y + a.z * bq.z + a.w * bq.w;
    }
    dot += __shfl_xor(dot, 1, 64);
    dot += __shfl_xor(dot, 2, 64);
    int g = lane >> 2;
    int rank = 0;
    #pragma unroll
    for (int j = 0; j < KSEL; ++j) {
        float vj = __shfl(dot, j * 4, 64);
        int   qj = __shfl(my_q, j * 4, 64);
        if (j != g && qj >= 0 && (vj > dot || (vj == dot && qj < my_q))) ++rank;
    }
    bool keep = ((lane & 3) == 0) && (my_q >= 0) && (rank < KNN);
    unsigned long long mask = __ballot(keep);
    int pos = __popcll(mask & ((1ull << lane) - 1));
    if (keep) out12[pos] = my_q;
}

// -- kernel 3 (fallback): standalone top-k ------------------------------------
__global__ void __launch_bounds__(256) k_topk7(const ushort* __restrict__ simh,
                                               const float* __restrict__ xn,
                                               int* __restrict__ knn,
                                               size_t simstride, size_t xstride) {
    __shared__ unsigned cand[4][64];
    __shared__ int ccnt[4];
    int wv = threadIdx.x >> 6, lane = threadIdx.x & 63;
    int row = blockIdx.x * 4 + wv;
    int b = row / NP, p = row % NP;
    dev_topk_row(simh + (size_t)b * simstride + (size_t)p * NP,
                 xn + (size_t)b * xstride, p, cand[wv], &ccnt[wv], lane,
                 knn + (size_t)row * KNN);
}

// ---- edge body: one point per wave; 3-deep gather ring + setprio MFMA --------
__device__ __forceinline__ bf16x8 packh2(bf16x8 u, bf16x8 v) {
    union { bf16x8 v8; ushort us[8]; } U, V, R;
    U.v8 = u; V.v8 = v;
    #pragma unroll
    for (int i = 0; i < 8; i += 2) {
        float a0 = __uint_as_float((unsigned)U.us[i] << 16)
                 + __uint_as_float((unsigned)V.us[i] << 16);
        float a1 = __uint_as_float((unsigned)U.us[i + 1] << 16)
                 + __uint_as_float((unsigned)V.us[i + 1] << 16);
        __hip_bfloat162 h2 = __float22bfloat162_rn(make_float2(lrelu(a0), lrelu(a1)));
        R.us[i]     = *reinterpret_cast<const ushort*>(&h2.x);
        R.us[i + 1] = *reinterpret_cast<const ushort*>(&h2.y);
    }
    return R.v8;
}

__device__ __forceinline__ void dev_edge_point(const ushort* __restrict__ up,
                                               const ushort* __restrict__ vv,
                                               int q0, int pt0,
                                               ushort (*w2s)[200], float* aggsw,
                                               const float* __restrict__ b2,
                                               const float* __restrict__ gamma,
                                               const float* __restrict__ beta,
                                               float* __restrict__ out,
                                               int l, int lg, int lr) {
    int b = pt0 / NP;
    const ushort* u0p = up + (size_t)pt0 * NC + 8 * lg;
    const ushort* v0p = vv + ((size_t)b * NP + q0) * NC + 8 * lg;

    f32x4 acc[12];
    #pragma unroll
    for (int nt = 0; nt < 12; ++nt) acc[nt] = (f32x4){0.f, 0.f, 0.f, 0.f};

    bf16x8 sU[3], sV[3];
#define LDST(ph, ks) do { \
        sU[ph] = *reinterpret_cast<const bf16x8*>(u0p + (ks) * 32); \
        sV[ph] = *reinterpret_cast<const bf16x8*>(v0p + (ks) * 32); \
    } while (0)

    LDST(0, 0); LDST(1, 1); LDST(2, 2);
    #pragma unroll
    for (int ks = 0; ks < 6; ++ks) {
        int ph = ks % 3;
        bf16x8 a0 = packh2(sU[ph], sV[ph]);
        if (ks < 3) LDST(ph, ks + 3);
        __builtin_amdgcn_s_setprio(1);
        #pragma unroll
        for (int nt = 0; nt < 12; ++nt) {
            bf16x8 bfr = *reinterpret_cast<const bf16x8*>(&w2s[nt * 16 + lr][ks * 32 + lg * 8]);
            acc[nt] = __builtin_amdgcn_mfma_f32_16x16x32_bf16(a0, bfr, acc[nt], 0, 0, 0);
        }
        __builtin_amdgcn_s_setprio(0);
    }
#undef LDST

    #pragma unroll
    for (int nt = 0; nt < 12; ++nt) {
        float bb = b2[nt * 16 + lr];
        float s = 0.f;
        if (lg < 3) {
            #pragma unroll
            for (int j = 0; j < 4; ++j) s += lrelu(acc[nt][j] + bb);
        }
        s += __shfl_xor(s, 16, 64);
        s += __shfl_xor(s, 32, 64);
        if (lg == 0) aggsw[nt * 16 + lr] = s * (1.0f / KNN);
    }
    asm volatile("s_waitcnt lgkmcnt(0)" ::: "memory");

    float a0 = aggsw[l], a1 = aggsw[l + 64], a2 = aggsw[l + 128];
    float s = a0 + a1 + a2;
    #pragma unroll
    for (int off = 32; off; off >>= 1) s += __shfl_xor(s, off, 64);
    float mu = s / (float)NC;
    float d0 = a0 - mu, d1 = a1 - mu, d2 = a2 - mu;
    float vs = d0 * d0 + d1 * d1 + d2 * d2;
    #pragma unroll
    for (int off = 32; off; off >>= 1) vs += __shfl_xor(vs, off, 64);
    float rstd = 1.0f / sqrtf(vs / (float)NC + 1e-5f);
    float* o = out + (size_t)pt0 * NC;
    o[l]       = d0 * rstd * gamma[l]       + beta[l];
    o[l + 64]  = d1 * rstd * gamma[l + 64]  + beta[l + 64];
    o[l + 128] = d2 * rstd * gamma[l + 128] + beta[l + 128];
}

#define EW 16   // waves/block, 1 point each

// ---- kernel 3+5 fused: early W2 barrier, then wave-independent topk->edge ----
__global__ void __launch_bounds__(1024, 4) k_topkedge(const ushort* __restrict__ simh,
                                                      const float* __restrict__ xn,
                                                      const ushort* __restrict__ up,
                                                      const ushort* __restrict__ vv,
                                                      const ushort* __restrict__ w2t,
                                                      const float* __restrict__ b2,
                                                      const float* __restrict__ gamma,
                                                      const float* __restrict__ beta,
                                                      float* __restrict__ out) {
    __shared__ ushort w2s[NC][200];    // 76.8 KB
    __shared__ float aggs[EW][NC];     // 12.3 KB
    __shared__ unsigned cand[EW][64];  // 4 KB
    __shared__ int knn_s[EW][KNN];     // 0.75 KB
    __shared__ int ccnt[EW];
    int t = threadIdx.x;
    int wv = t >> 6, l = t & 63;
    int lg = l >> 4, lr = l & 15;

    int pt0 = blockIdx.x * EW + wv;
    int b = pt0 / NP, p = pt0 % NP;

    for (int i = t; i < NC * 24; i += 1024) {
        int r_ = i / 24, c_ = i % 24;
        *reinterpret_cast<bf16x8*>(&w2s[r_][c_ * 8]) =
            *reinterpret_cast<const bf16x8*>(&w2t[(size_t)r_ * NC + c_ * 8]);
    }
    __syncthreads();   // only block-wide barrier (w2s visibility)

    dev_topk_row(simh + (size_t)b * ((size_t)NP * NP) + (size_t)p * NP,
                 xn + (size_t)b * ((size_t)NP * NC), p, cand[wv], &ccnt[wv],
                 l, knn_s[wv]);
    asm volatile("s_waitcnt lgkmcnt(0)" ::: "memory");   // same-wave knn_s RAW

    int lre = l & 15; lre = lre < KNN ? lre : KNN - 1;
    int q0 = knn_s[wv][lre];
    dev_edge_point(up, vv, q0, pt0, w2s, aggs[wv], b2, gamma, beta, out, l, lg, lr);
}

// ---- standalone edge kernel (fallback path) ----------------------------------
__global__ void __launch_bounds__(1024, 4) k_edge7(const ushort* __restrict__ up,
                                                   const ushort* __restrict__ vv,
                                                   const int* __restrict__ knn,
                                                   const ushort* __restrict__ w2t,
                                                   const float* __restrict__ b2,
                                                   const float* __restrict__ gamma,
                                                   const float* __restrict__ beta,
                                                   float* __restrict__ out) {
    __shared__ ushort w2s[NC][200];
    __shared__ float aggs[EW][NC];
    int t = threadIdx.x;
    int wv = t >> 6, l = t & 63;
    int lg = l >> 4, lr = l & 15;

    int pt0 = blockIdx.x * EW + wv;
    int lre = lr < KNN ? lr : KNN - 1;
    int q0 = knn[(size_t)pt0 * KNN + lre];

    for (int i = t; i < NC * 24; i += 1024) {
        int r_ = i / 24, c_ = i % 24;
        *reinterpret_cast<bf16x8*>(&w2s[r_][c_ * 8]) =
            *reinterpret_cast<const bf16x8*>(&w2t[(size_t)r_ * NC + c_ * 8]);
    }
    __syncthreads();

    dev_edge_point(up, vv, q0, pt0, w2s, aggs[wv], b2, gamma, beta, out, l, lg, lr);
}

extern "C" void kernel_launch(void* const* d_in, const int* in_sizes, int n_in,
                              void* d_out, int out_size, void* d_ws, size_t ws_size,
                              hipStream_t stream) {
    const float* nodes = (const float*)d_in[0];
    const float* W1    = (const float*)d_in[1];
    const float* b1    = (const float*)d_in[2];
    const float* W2    = (const float*)d_in[3];
    const float* b2    = (const float*)d_in[4];
    const float* gamma = (const float*)d_in[5];
    const float* beta  = (const float*)d_in[6];
    float* out = (float*)d_out;

    const size_t BPC = (size_t)NB * NP * NC;
    float*  xn  = (float*)d_ws;                        // B*P*C f32
    ushort* up  = (ushort*)(xn + BPC);                 // B*P*C bf16
    ushort* vv  = up + BPC;                            // B*P*C bf16
    ushort* xh  = vv + BPC;                            // B*P*C bf16 (normalized)
    ushort* xb  = xh + BPC;                            // B*P*C bf16 (raw)
    int*    knn = (int*)(xb + BPC);                    // B*P*K (fallback only)
    ushort* w2t = (ushort*)(knn + (size_t)NB * NP * KNN); // C*C bf16
    ushort* w1t = w2t + (size_t)NC * NC;               // 2C*C bf16
    ushort* simh = (ushort*)(((uintptr_t)(w1t + (size_t)2 * NC * NC) + 15) & ~(uintptr_t)15);

    size_t fixed_bytes = (size_t)((char*)simh - (char*)d_ws);
    bool full = ws_size >= fixed_bytes + (size_t)NB * NP * NP * 2;

    int prep_grid = NB * NP / 4 + 2 * NC * NC / 256 + NC * NC / 256;   // 2048+288+144
    k_prep<<<prep_grid, 256, 0, stream>>>(nodes, W1, W2, xn, xh, xb, w1t, w2t);
    if (full) {
        k_uvsim<<<NB * NP / UVM + 16 * NB * (NP / 128), 256, 36864, stream>>>(
            xb, w1t, b1, up, vv, xh, simh);
        k_topkedge<<<NB * NP / EW, 1024, 0, stream>>>(simh, xn, up, vv, w2t,
                                                      b2, gamma, beta, out);
    } else {
        k_uv2<<<NB * NP / UVM, 256, 0, stream>>>(xb, w1t, b1, up, vv);
        for (int b = 0; b < NB; ++b) {
            k_sim4<<<dim3(NP / 128, NP / 128, 1), 256, 0, stream>>>(xh + (size_t)b * NP * NC, simh, 0, 0);
            k_topk7<<<NP / 4, 256, 0, stream>>>(simh, xn + (size_t)b * NP * NC,
                                                knn + (size_t)b * NP * KNN, 0, 0);
        }
        k_edge7<<<NB * NP / EW, 1024, 0, stream>>>(up, vv, knn, w2t, b2, gamma, beta, out);
    }
}